// Round 4
// baseline (184.285 us; speedup 1.0000x reference)
//
#include <hip/hip_runtime.h>

// Problem constants (B,C,D,H,W) = (2,4,96,160,160)
#define NB 2
#define NC 4
#define ND 96
#define NH 160
#define NW 160

// Math (verified exact rounds 1-3): sy == sz (identical 2D 3x3 kernels),
// depth padding adds only zero slices, sobel(p)-sobel(t) = sobel(q) with
// q = softmax(pred) - onehot(target):
//   loss = sum(gx^2 + 2*gy^2) * SCALE
// separable: d = q[x+1]-q[x-1], s = q[x-1]+2q[x]+q[x+1],
//            gx = d[y-1]+2d[y]+d[y+1], gy = s[y+1]-s[y-1].
//
// Structure: full-width bands of TH=8 output rows. Staging is float4/int4
// vectorized, fixed-trip, fully unrolled (all 10 global loads issue before
// any wait -> one latency exposure). LDS = 25.6 KB -> 6 blocks/CU.
constexpr int TH    = 8;              // output rows per band
constexpr int SR    = TH + 2;         // staged rows (vertical halo)
constexpr int NBAND = NH / TH;        // 20 bands per slice
constexpr int PITCH = NW;             // staged row pitch in float4 cells
constexpr int NCELL = SR * PITCH;     // 1600 cells (float4 each) = 25.6 KB
constexpr int NSLOT = NCELL / 4;      // 400 4-pixel staging slots
constexpr float SCALE = 1.0f / (2.0f * 98.0f * 162.0f * 162.0f * 4.0f);

// 4-group rotation swizzle: keeps each thread's 4 consecutive ds_write_b128
// (64-B stride across lanes) spread over banks; reads stay a permutation of
// consecutive cells (conflict-free pattern).
__device__ __forceinline__ int cell(int i) {
    return (i & ~3) | ((i + (i >> 2)) & 3);
}

__device__ __forceinline__ void stage_slot(float4* __restrict__ q4s,
                                           const float4* p, const int4& tg,
                                           bool valid, int flat0) {
    #pragma unroll
    for (int k = 0; k < 4; ++k) {
        float4 v = make_float4(0.f, 0.f, 0.f, 0.f);
        if (valid) {
            const float p0 = ((const float*)&p[0])[k];
            const float p1 = ((const float*)&p[1])[k];
            const float p2 = ((const float*)&p[2])[k];
            const float p3 = ((const float*)&p[3])[k];
            const int   t  = ((const int*)&tg)[k];
            const float m  = fmaxf(fmaxf(p0, p1), fmaxf(p2, p3));
            const float e0 = __expf(p0 - m);
            const float e1 = __expf(p1 - m);
            const float e2 = __expf(p2 - m);
            const float e3 = __expf(p3 - m);
            const float inv = 1.0f / (e0 + e1 + e2 + e3);
            v.x = e0 * inv - (t == 0 ? 1.f : 0.f);
            v.y = e1 * inv - (t == 1 ? 1.f : 0.f);
            v.z = e2 * inv - (t == 2 ? 1.f : 0.f);
            v.w = e3 * inv - (t == 3 ? 1.f : 0.f);
        }
        q4s[cell(flat0 + k)] = v;
    }
}

__global__ __launch_bounds__(256, 6) void boundary_loss_kernel(
    const float* __restrict__ pred,   // (B,C,D,H,W) f32
    const int*   __restrict__ target, // (B,D,H,W) i32
    float* __restrict__ out)          // scalar, pre-zeroed
{
    __shared__ float4 q4s[NCELL];     // 25.6 KB, swizzled class-interleaved
    __shared__ float wsum[4];

    const int tid   = threadIdx.x;
    const int slice = blockIdx.y;     // b*ND + d
    const int b     = slice / ND;
    const int d     = slice - b * ND;
    const int y0    = blockIdx.x * TH;

    const size_t cs4   = (size_t)ND * NH * NW / 4;   // class stride in float4
    const size_t pbase = ((size_t)b * NC * ND + d) * (size_t)(NH * NW);
    const size_t tbase = ((size_t)b * ND + d) * (size_t)(NH * NW);

    // ---- Load phase: slot A = tid, slot B = tid + 256 (tid < 144) ----
    const int  rA   = tid / 40;
    const int  cA   = tid - rA * 40;
    const int  gyA  = y0 - 1 + rA;
    const bool vA   = (gyA >= 0) && (gyA < NH);
    const int  gyAc = min(max(gyA, 0), NH - 1);

    const int  sB   = tid + 256;
    const bool hasB = (sB < NSLOT);
    const int  rB   = sB / 40;
    const int  cB   = sB - rB * 40;
    const int  gyB  = y0 - 1 + rB;
    const bool vB   = hasB && (gyB >= 0) && (gyB < NH);
    const int  gyBc = min(max(gyB, 0), NH - 1);

    float4 pA[4], pB[4];
    int4   tA = make_int4(0, 0, 0, 0), tB = make_int4(0, 0, 0, 0);
    {
        const float4* pp = (const float4*)(pred + pbase + (size_t)gyAc * NW) + cA;
        pA[0] = pp[0];
        pA[1] = pp[cs4];
        pA[2] = pp[2 * cs4];
        pA[3] = pp[3 * cs4];
        tA = ((const int4*)(target + tbase + (size_t)gyAc * NW))[cA];
    }
    if (hasB) {
        const float4* pp = (const float4*)(pred + pbase + (size_t)gyBc * NW) + cB;
        pB[0] = pp[0];
        pB[1] = pp[cs4];
        pB[2] = pp[2 * cs4];
        pB[3] = pp[3 * cs4];
        tB = ((const int4*)(target + tbase + (size_t)gyBc * NW))[cB];
    } else {
        pB[0] = pB[1] = pB[2] = pB[3] = make_float4(0.f, 0.f, 0.f, 0.f);
    }

    // ---- Softmax + stage into LDS ----
    stage_slot(q4s, pA, tA, vA, rA * PITCH + 4 * cA);
    if (hasB) stage_slot(q4s, pB, tB, vB, rB * PITCH + 4 * cB);
    __syncthreads();

    // ---- Vertical rolling Sobel: thread t owns column x = t (t < 160) ----
    float acc = 0.f;
    if (tid < NW) {
        float smm[NC], sm[NC], dmm[NC], dm[NC];
        #pragma unroll
        for (int c = 0; c < NC; ++c) { smm[c] = sm[c] = dmm[c] = dm[c] = 0.f; }

        #pragma unroll
        for (int t = 0; t < SR; ++t) {
            const int base = t * PITCH + tid;
            const float4 qm = q4s[cell(base)];
            float4 ql = make_float4(0.f, 0.f, 0.f, 0.f);
            float4 qr = make_float4(0.f, 0.f, 0.f, 0.f);
            if (tid > 0)      ql = q4s[cell(base - 1)];
            if (tid < NW - 1) qr = q4s[cell(base + 1)];
            const float* lf = (const float*)&ql;
            const float* mf = (const float*)&qm;
            const float* rf = (const float*)&qr;
            #pragma unroll
            for (int c = 0; c < NC; ++c) {
                const float sn = lf[c] + 2.f * mf[c] + rf[c];
                const float dn = rf[c] - lf[c];
                if (t >= 2) {
                    const float gx = dmm[c] + 2.f * dm[c] + dn;
                    const float gy = sn - smm[c];
                    acc += gx * gx + 2.f * gy * gy;
                }
                smm[c] = sm[c]; sm[c] = sn;
                dmm[c] = dm[c]; dm[c] = dn;
            }
        }
    }

    // ---- Block reduction -> one atomic per block ----
    #pragma unroll
    for (int off = 32; off > 0; off >>= 1)
        acc += __shfl_down(acc, off, 64);
    if ((tid & 63) == 0) wsum[tid >> 6] = acc;
    __syncthreads();
    if (tid == 0) {
        const float s = wsum[0] + wsum[1] + wsum[2] + wsum[3];
        atomicAdd(out, s * SCALE);
    }
}

extern "C" void kernel_launch(void* const* d_in, const int* in_sizes, int n_in,
                              void* d_out, int out_size, void* d_ws, size_t ws_size,
                              hipStream_t stream) {
    const float* pred   = (const float*)d_in[0];
    const int*   target = (const int*)d_in[1];
    float*       out    = (float*)d_out;

    // d_out is poisoned with 0xAA before every launch — zero the scalar first.
    hipMemsetAsync(out, 0, sizeof(float), stream);

    dim3 grid(NBAND, NB * ND);   // 20 x 192 = 3840 blocks
    boundary_loss_kernel<<<grid, 256, 0, stream>>>(pred, target, out);
}